// Round 4
// baseline (327.552 us; speedup 1.0000x reference)
//
#include <hip/hip_runtime.h>

#define D_MODEL 1024
#define NHEAD   16
#define DK      64
#define SEQ     2048
#define BATCH   4
#define MTOT    (BATCH * SEQ)   // 8192
#define NEG_INF (-1e30f)
#define QSCALE  0.18033688f     // 0.125 * log2(e): folds score scale + exp->exp2

typedef float    f32x4 __attribute__((ext_vector_type(4)));
typedef _Float16 half8 __attribute__((ext_vector_type(8)));

__device__ __forceinline__ unsigned hb(float f) {
    _Float16 h = (_Float16)f;
    return (unsigned)__builtin_bit_cast(unsigned short, h);
}
__device__ __forceinline__ uint2 pack4h(float a, float b, float c, float d) {
    uint2 r; r.x = hb(a) | (hb(b) << 16); r.y = hb(c) | (hb(d) << 16); return r;
}

// ---------------------------------------------------------------------------
// Transpose + fp32->f16:  src fp32 [R][C] -> dst f16 [C][R]
// ---------------------------------------------------------------------------
__global__ __launch_bounds__(256)
void transpose_cvt(const float* __restrict__ src, _Float16* __restrict__ dst,
                   int R, int C, long long sB, long long dB)
{
    __shared__ float tile[32][33];
    const int t = threadIdx.x;
    src += (long long)blockIdx.z * sB;
    dst += (long long)blockIdx.z * dB;
    const int r0 = blockIdx.y * 32, c0 = blockIdx.x * 32;
    const int lr = t >> 3, lc = (t & 7) * 4;

    float4 f = *(const float4*)&src[(long long)(r0 + lr) * C + c0 + lc];
    tile[lr][lc + 0] = f.x; tile[lr][lc + 1] = f.y;
    tile[lr][lc + 2] = f.z; tile[lr][lc + 3] = f.w;
    __syncthreads();
    uint2 o = pack4h(tile[lc + 0][lr], tile[lc + 1][lr],
                     tile[lc + 2][lr], tile[lc + 3][lr]);
    *(uint2*)&dst[(long long)(c0 + lr) * R + r0 + lc] = o;
}

// 4 weight transposes in one dispatch (z selects the weight)
__global__ __launch_bounds__(256)
void transpose_w4(const float* __restrict__ W0, const float* __restrict__ W1,
                  const float* __restrict__ W2, const float* __restrict__ W3,
                  _Float16* __restrict__ D0, _Float16* __restrict__ D1,
                  _Float16* __restrict__ D2, _Float16* __restrict__ D3)
{
    __shared__ float tile[32][33];
    const float* src; _Float16* dst;
    switch (blockIdx.z) {
        case 0: src = W0; dst = D0; break;
        case 1: src = W1; dst = D1; break;
        case 2: src = W2; dst = D2; break;
        default: src = W3; dst = D3; break;
    }
    const int t = threadIdx.x;
    const int r0 = blockIdx.y * 32, c0 = blockIdx.x * 32;
    const int lr = t >> 3, lc = (t & 7) * 4;
    float4 f = *(const float4*)&src[(long long)(r0 + lr) * D_MODEL + c0 + lc];
    tile[lr][lc + 0] = f.x; tile[lr][lc + 1] = f.y;
    tile[lr][lc + 2] = f.z; tile[lr][lc + 3] = f.w;
    __syncthreads();
    uint2 o = pack4h(tile[lc + 0][lr], tile[lc + 1][lr],
                     tile[lc + 2][lr], tile[lc + 3][lr]);
    *(uint2*)&dst[(long long)(c0 + lr) * D_MODEL + r0 + lc] = o;
}

// ---------------------------------------------------------------------------
// f16 MFMA GEMM:  C[m][n] = (sum_k A[m][k] * B^T[n][k] + bias[n]) * scale
// M=8192, N=K=1024. Tile 128x128, BK=32, 4 waves.
// OM=0: f16 row-major [m][1024]   (Q with scale, K with scale=1)
// OM=1: f16 transposed VT[b][n][l] (V)
// OM=2: fp32 transposed d_out[b][n][l] (final)
// ---------------------------------------------------------------------------
template<int OM>
__global__ __launch_bounds__(256)
void gemm_f16(const _Float16* __restrict__ A, const _Float16* __restrict__ B,
              const float* __restrict__ bias, void* __restrict__ Cout, float scale)
{
    __shared__ __align__(16) _Float16 As[128 * 32];
    __shared__ __align__(16) _Float16 Bs[128 * 32];

    const int t = threadIdx.x, w = t >> 6, l = t & 63;
    const int lo16 = l & 15, hi = l >> 4;
    const int bid = blockIdx.x;
    const int swz = (bid & 7) * 64 + (bid >> 3);
    const int bm = swz & 63, bn = swz >> 6;
    const int wr = w >> 1, wc = w & 1;

    f32x4 acc[4][4];
#pragma unroll
    for (int mi = 0; mi < 4; ++mi)
#pragma unroll
        for (int ni = 0; ni < 4; ++ni) acc[mi][ni] = (f32x4){0.f, 0.f, 0.f, 0.f};

    const int srow   = l >> 2;
    const int schunk = (l & 3) ^ ((l >> 3) & 3);
    const _Float16* Ag = A + (long long)(bm * 128 + w * 32 + srow) * 1024 + schunk * 8;
    const _Float16* Bg = B + (long long)(bn * 128 + w * 32 + srow) * 1024 + schunk * 8;
    const int ldsOff = (w * 32) * 32;
    const int xr = (lo16 >> 1) & 3;

    for (int k0 = 0; k0 < 1024; k0 += 32) {
        __syncthreads();
        __builtin_amdgcn_global_load_lds(reinterpret_cast<const unsigned int*>(Ag + k0),
                                         reinterpret_cast<unsigned int*>(&As[ldsOff]), 16, 0, 0);
        __builtin_amdgcn_global_load_lds(reinterpret_cast<const unsigned int*>(Ag + k0 + 16 * 1024),
                                         reinterpret_cast<unsigned int*>(&As[ldsOff + 16 * 32]), 16, 0, 0);
        __builtin_amdgcn_global_load_lds(reinterpret_cast<const unsigned int*>(Bg + k0),
                                         reinterpret_cast<unsigned int*>(&Bs[ldsOff]), 16, 0, 0);
        __builtin_amdgcn_global_load_lds(reinterpret_cast<const unsigned int*>(Bg + k0 + 16 * 1024),
                                         reinterpret_cast<unsigned int*>(&Bs[ldsOff + 16 * 32]), 16, 0, 0);
        __syncthreads();

        half8 af[4], bf[4];
#pragma unroll
        for (int mi = 0; mi < 4; ++mi)
            af[mi] = *(const half8*)&As[(wr * 64 + mi * 16 + lo16) * 32 + ((hi ^ xr) << 3)];
#pragma unroll
        for (int ni = 0; ni < 4; ++ni)
            bf[ni] = *(const half8*)&Bs[(wc * 64 + ni * 16 + lo16) * 32 + ((hi ^ xr) << 3)];
#pragma unroll
        for (int mi = 0; mi < 4; ++mi)
#pragma unroll
            for (int ni = 0; ni < 4; ++ni)
                acc[mi][ni] = __builtin_amdgcn_mfma_f32_16x16x32_f16(af[mi], bf[ni], acc[mi][ni], 0, 0, 0);
    }

    if constexpr (OM == 0) {
        _Float16* C = (_Float16*)Cout;
#pragma unroll
        for (int mi = 0; mi < 4; ++mi) {
            const int m = bm * 128 + wr * 64 + mi * 16 + hi * 4;
#pragma unroll
            for (int ni = 0; ni < 4; ++ni) {
                const int n = bn * 128 + wc * 64 + ni * 16 + lo16;
                const float bv = bias[n];
#pragma unroll
                for (int r = 0; r < 4; ++r)
                    C[(long long)(m + r) * D_MODEL + n] = (_Float16)((acc[mi][ni][r] + bv) * scale);
            }
        }
    } else if constexpr (OM == 1) {
        _Float16* C = (_Float16*)Cout;
#pragma unroll
        for (int mi = 0; mi < 4; ++mi) {
            const int m  = bm * 128 + wr * 64 + mi * 16 + hi * 4;
            const int bo = m >> 11;
            const int ll = m & (SEQ - 1);
#pragma unroll
            for (int ni = 0; ni < 4; ++ni) {
                const int n = bn * 128 + wc * 64 + ni * 16 + lo16;
                const float bv = bias[n];
                uint2 o = pack4h(acc[mi][ni][0] + bv, acc[mi][ni][1] + bv,
                                 acc[mi][ni][2] + bv, acc[mi][ni][3] + bv);
                *(uint2*)&C[((long long)bo * D_MODEL + n) * SEQ + ll] = o;
            }
        }
    } else {
        float* C = (float*)Cout;
#pragma unroll
        for (int mi = 0; mi < 4; ++mi) {
            const int m  = bm * 128 + wr * 64 + mi * 16 + hi * 4;
            const int bo = m >> 11;
            const int ll = m & (SEQ - 1);
#pragma unroll
            for (int ni = 0; ni < 4; ++ni) {
                const int n = bn * 128 + wc * 64 + ni * 16 + lo16;
                const float bv = bias[n];
                float4 o;
                o.x = acc[mi][ni][0] + bv; o.y = acc[mi][ni][1] + bv;
                o.z = acc[mi][ni][2] + bv; o.w = acc[mi][ni][3] + bv;
                *(float4*)&C[((long long)bo * D_MODEL + n) * SEQ + ll] = o;
            }
        }
    }
}

// ---------------------------------------------------------------------------
// Flash attention, f16 in/out, double-buffered global_load_lds staging.
// qh: f16 [m][1024] pre-scaled by 0.125*log2e; kh: f16 [m][1024];
// VT: f16 [b][1024][2048]. Output attnO: f16 [m][1024].
// grid: 1024 blocks (XCD-swizzled), 256 threads (4 waves x 32 q-rows).
// ---------------------------------------------------------------------------
__global__ __launch_bounds__(256)
void attn_mfma(const _Float16* __restrict__ qh, const _Float16* __restrict__ kh,
               const _Float16* __restrict__ VT, const int* __restrict__ mask,
               _Float16* __restrict__ attnO)
{
    __shared__ __align__(16) _Float16 ks[2][64 * 64];
    __shared__ __align__(16) _Float16 vs[2][64 * 64];
    __shared__ __align__(16) _Float16 pT[4][16][72];
    __shared__ float sbias[2][64];

    const int t    = threadIdx.x;
    const int w    = t >> 6;
    const int l    = t & 63;
    const int lo16 = l & 15;
    const int hi   = l >> 4;

    // XCD-bijective swizzle: 128 consecutive ids per XCD -> 8 (b,h) pairs each
    const int id = blockIdx.x;
    const int i  = (id & 7) * 128 + (id >> 3);
    const int bh = i >> 4, qb = i & 15;
    const int b = bh >> 4, h = bh & 15;
    const int q0 = qb * 128 + w * 32;

    const _Float16* kbase = kh + (long long)(b * SEQ) * D_MODEL + h * DK;
    const _Float16* vbase = VT + ((long long)b * D_MODEL + h * DK) * SEQ;

    // Q fragments (pre-scaled f16, direct 16B loads)
    half8 qf[2][2];
#pragma unroll
    for (int nt = 0; nt < 2; ++nt)
#pragma unroll
        for (int kk = 0; kk < 2; ++kk)
            qf[nt][kk] = *(const half8*)&qh[(long long)(b * SEQ + q0 + nt * 16 + lo16) * D_MODEL
                                            + h * DK + kk * 32 + hi * 8];

    f32x4 oacc[2][4];
#pragma unroll
    for (int nt = 0; nt < 2; ++nt)
#pragma unroll
        for (int mt = 0; mt < 4; ++mt) oacc[nt][mt] = (f32x4){0.f, 0.f, 0.f, 0.f};
    float mrun[2] = {NEG_INF, NEG_INF};
    float lsum[2] = {0.f, 0.f};

    const int srow = l >> 3;          // 0..7 within 8-row staging span
    const int scol = (l & 7) * 8;     // halfs

    // stage one K/V tile into buffer sel (wave w stages rows w*16..w*16+15)
    auto stage = [&](int sel, int kt) {
#pragma unroll
        for (int j = 0; j < 2; ++j) {
            const int row = w * 16 + j * 8;
            __builtin_amdgcn_global_load_lds(
                reinterpret_cast<const unsigned int*>(
                    kbase + (long long)(kt * 64 + row + srow) * D_MODEL + scol),
                reinterpret_cast<unsigned int*>(&ks[sel][row * 64]), 16, 0, 0);
            __builtin_amdgcn_global_load_lds(
                reinterpret_cast<const unsigned int*>(
                    vbase + (long long)(row + srow) * SEQ + kt * 64 + scol),
                reinterpret_cast<unsigned int*>(&vs[sel][row * 64]), 16, 0, 0);
        }
        if (t < 64) sbias[sel][t] = mask[b * SEQ + kt * 64 + t] ? 0.f : NEG_INF;
    };

    stage(0, 0);
    __syncthreads();
    int cur = 0;

    for (int kt = 0; kt < SEQ / 64; ++kt) {
        if (kt + 1 < SEQ / 64) stage(cur ^ 1, kt + 1);

        half8 kf[4][2], vf[4][2];
        f32x4 sb[4];
#pragma unroll
        for (int mt = 0; mt < 4; ++mt) {
#pragma unroll
            for (int kk = 0; kk < 2; ++kk) {
                kf[mt][kk] = *(const half8*)&ks[cur][(mt * 16 + lo16) * 64 + kk * 32 + hi * 8];
                vf[mt][kk] = *(const half8*)&vs[cur][(mt * 16 + lo16) * 64 + kk * 32 + hi * 8];
            }
            sb[mt] = *(const f32x4*)&sbias[cur][mt * 16 + hi * 4];
        }

#pragma unroll
        for (int nt = 0; nt < 2; ++nt) {
            // QK^T (swapped): scores^T[key][q], log2 domain
            f32x4 sc[4];
            __builtin_amdgcn_s_setprio(1);
#pragma unroll
            for (int mt = 0; mt < 4; ++mt) {
                f32x4 a = (f32x4){0.f, 0.f, 0.f, 0.f};
                a = __builtin_amdgcn_mfma_f32_16x16x32_f16(kf[mt][0], qf[nt][0], a, 0, 0, 0);
                a = __builtin_amdgcn_mfma_f32_16x16x32_f16(kf[mt][1], qf[nt][1], a, 0, 0, 0);
                sc[mt] = a;
            }
            __builtin_amdgcn_s_setprio(0);

            float p[4][4];
            float tmax = NEG_INF;
#pragma unroll
            for (int mt = 0; mt < 4; ++mt)
#pragma unroll
                for (int r = 0; r < 4; ++r) {
                    float s = sc[mt][r] + sb[mt][r];
                    p[mt][r] = s;
                    tmax = fmaxf(tmax, s);
                }
            tmax = fmaxf(tmax, __shfl_xor(tmax, 16));
            tmax = fmaxf(tmax, __shfl_xor(tmax, 32));

            // defer-max: rescale only when the running max grows by > 8 (log2)
            if (!__all(tmax - mrun[nt] <= 8.f)) {
                float mnew = fmaxf(mrun[nt], tmax);
                float corr = exp2f(mrun[nt] - mnew);
                lsum[nt] *= corr;
#pragma unroll
                for (int mt = 0; mt < 4; ++mt) oacc[nt][mt] *= corr;
                mrun[nt] = mnew;
            }

            float psum = 0.f;
#pragma unroll
            for (int mt = 0; mt < 4; ++mt)
#pragma unroll
                for (int r = 0; r < 4; ++r) {
                    float e = exp2f(p[mt][r] - mrun[nt]);
                    p[mt][r] = e;
                    psum += e;
                }
            psum += __shfl_xor(psum, 16);
            psum += __shfl_xor(psum, 32);
            lsum[nt] += psum;

            // P^T re-layout through per-wave LDS
#pragma unroll
            for (int mt = 0; mt < 4; ++mt)
                *(uint2*)&pT[w][lo16][mt * 16 + hi * 4] =
                    pack4h(p[mt][0], p[mt][1], p[mt][2], p[mt][3]);
            asm volatile("s_waitcnt lgkmcnt(0)" ::: "memory");
            __builtin_amdgcn_sched_barrier(0);
            half8 pf0 = *(const half8*)&pT[w][lo16][hi * 8];
            half8 pf1 = *(const half8*)&pT[w][lo16][32 + hi * 8];

            __builtin_amdgcn_s_setprio(1);
#pragma unroll
            for (int mt = 0; mt < 4; ++mt) {
                oacc[nt][mt] = __builtin_amdgcn_mfma_f32_16x16x32_f16(vf[mt][0], pf0, oacc[nt][mt], 0, 0, 0);
                oacc[nt][mt] = __builtin_amdgcn_mfma_f32_16x16x32_f16(vf[mt][1], pf1, oacc[nt][mt], 0, 0, 0);
            }
            __builtin_amdgcn_s_setprio(0);
        }

        __syncthreads();   // drains vmcnt (staged tile landed) + lgkm
        cur ^= 1;
    }

    // epilogue: normalize, LDS-bounce, write f16 [m][1024]
#pragma unroll
    for (int nt = 0; nt < 2; ++nt) {
        float inv = 1.f / lsum[nt];
#pragma unroll
        for (int mt = 0; mt < 4; ++mt)
            *(uint2*)&pT[w][lo16][mt * 16 + hi * 4] =
                pack4h(oacc[nt][mt][0] * inv, oacc[nt][mt][1] * inv,
                       oacc[nt][mt][2] * inv, oacc[nt][mt][3] * inv);
        asm volatile("s_waitcnt lgkmcnt(0)" ::: "memory");
        __builtin_amdgcn_sched_barrier(0);
#pragma unroll
        for (int j = 0; j < 2; ++j) {
            int idx = l + j * 64;
            int qr = idx >> 3, c8 = idx & 7;
            half8 row = *(const half8*)&pT[w][qr][c8 * 8];
            *(half8*)&attnO[(long long)(b * SEQ + q0 + nt * 16 + qr) * D_MODEL + h * DK + c8 * 8] = row;
        }
    }
}

// ---------------------------------------------------------------------------
extern "C" void kernel_launch(void* const* d_in, const int* in_sizes, int n_in,
                              void* d_out, int out_size, void* d_ws, size_t ws_size,
                              hipStream_t stream)
{
    const float* x    = (const float*)d_in[0];
    const int*   mask = (const int*)d_in[1];
    const float* Wq   = (const float*)d_in[2];
    const float* bq   = (const float*)d_in[3];
    const float* Wk   = (const float*)d_in[4];
    const float* bk   = (const float*)d_in[5];
    const float* Wv   = (const float*)d_in[6];
    const float* bv   = (const float*)d_in[7];
    const float* Wf   = (const float*)d_in[8];
    const float* bf   = (const float*)d_in[9];
    float* out = (float*)d_out;

    // workspace (f16 everywhere): xt | 4xWT | qh | kh | VT | attnO  = 88 MB
    _Float16* xt    = (_Float16*)d_ws;                     // [8192][1024]
    _Float16* WTq   = xt    + (size_t)MTOT * D_MODEL;
    _Float16* WTk   = WTq   + (size_t)D_MODEL * D_MODEL;
    _Float16* WTv   = WTk   + (size_t)D_MODEL * D_MODEL;
    _Float16* WTf   = WTv   + (size_t)D_MODEL * D_MODEL;
    _Float16* qh    = WTf   + (size_t)D_MODEL * D_MODEL;   // [8192][1024], pre-scaled
    _Float16* khb   = qh    + (size_t)MTOT * D_MODEL;      // [8192][1024]
    _Float16* VTb   = khb   + (size_t)MTOT * D_MODEL;      // [4][1024][2048]
    _Float16* attnO = VTb   + (size_t)MTOT * D_MODEL;      // [8192][1024]

    dim3 gTx(SEQ / 32, D_MODEL / 32, BATCH);
    transpose_cvt<<<gTx, 256, 0, stream>>>(x, xt, D_MODEL, SEQ,
                                           (long long)D_MODEL * SEQ, (long long)SEQ * D_MODEL);
    dim3 gTw(D_MODEL / 32, D_MODEL / 32, 4);
    transpose_w4<<<gTw, 256, 0, stream>>>(Wq, Wk, Wv, Wf, WTq, WTk, WTv, WTf);

    gemm_f16<0><<<512, 256, 0, stream>>>(xt, WTq, bq, qh,  QSCALE);  // Q (scaled)
    gemm_f16<0><<<512, 256, 0, stream>>>(xt, WTk, bk, khb, 1.0f);    // K
    gemm_f16<1><<<512, 256, 0, stream>>>(xt, WTv, bv, VTb, 1.0f);    // V -> VT

    attn_mfma<<<1024, 256, 0, stream>>>(qh, khb, VTb, mask, attnO);

    gemm_f16<2><<<512, 256, 0, stream>>>(attnO, WTf, bf, out, 1.0f); // final -> d_out
}